// Round 1
// baseline (2077.511 us; speedup 1.0000x reference)
//
#include <hip/hip_runtime.h>

#define LAMF 0.1f
#define LRF  0.01f
#define B1F  0.9f
#define B2F  0.99f
#define EPSF 1e-8f

constexpr int NB = 32, H = 256, W = 256, C = 64;
constexpr int OH = 61, OW = 61;
constexpr int PLANE = OH * OW;            // 3721
constexpr int USZ = NB * C * PLANE;       // 7,620,608 floats
constexpr int ESZ = NB * H * W;           // 2,097,152 floats
constexpr int FSZ = 16 * 16 * 64;         // 16384 floats

// ---------------------------------------------------------------------------
// Permute filter for ek: f1[r][c][ii][s][k] = filt[4*(3-ii)+s][4*(3-k)+r][c]
// ---------------------------------------------------------------------------
__global__ __launch_bounds__(256) void permute_filt(const float* __restrict__ filt,
                                                    float* __restrict__ f1) {
    int o = blockIdx.x * 256 + threadIdx.x;
    if (o >= FSZ) return;
    int k  = o & 3;
    int s  = (o >> 2) & 3;
    int ii = (o >> 4) & 3;
    int c  = (o >> 6) & 63;
    int r  = o >> 12;
    int kh = 4 * (3 - ii) + s;
    int kw = 4 * (3 - k) + r;
    f1[o] = filt[(kh * 16 + kw) * 64 + c];
}

// ---------------------------------------------------------------------------
// Kernel 1: e[b,y,x] = img[b,y,x] - sum_{di,dj,c} act[b, p0-di, q-dj, c] *
//                                   filt[4di+s, 4dj+r, c]
// block = (b, p0) band of 4 rows (y = 4*p0+s), thread = (r = wave, q = lane)
// u layout: [b][c][61][61]; act staged in LDS (two 32-channel chunks).
// LDS rows stride 64, slots [0..2] are j=-3..-1 zero pad; reads that run past
// slot 63 land in the NEXT row's zero pad (row 128 = all zeros terminator).
// ---------------------------------------------------------------------------
__global__ __launch_bounds__(256) void ek(const float* __restrict__ u,
                                          const float* __restrict__ img,
                                          const float* __restrict__ f1,
                                          float* __restrict__ e) {
    __shared__ __align__(16) float lds[129 * 64];
    int bx  = blockIdx.x;
    int b   = bx >> 6;
    int p0  = bx & 63;
    int tid = threadIdx.x;
    int r   = tid >> 6;
    int q   = tid & 63;
    int ru  = __builtin_amdgcn_readfirstlane(r);

    float acc0 = 0.f, acc1 = 0.f, acc2 = 0.f, acc3 = 0.f;

    for (int chunk = 0; chunk < 2; ++chunk) {
        int c0 = chunk * 32;
        __syncthreads();
        // stage act chunk: rows = ii*32+cc (ii=0..3 -> i=p0-3+ii), 64 slots/row
        for (int idx = tid; idx < 129 * 64; idx += 256) {
            int row = idx >> 6, slot = idx & 63;
            float val = 0.f;
            if (row < 128) {
                int ii = row >> 5, cc = row & 31;
                int i = p0 - 3 + ii;
                int j = slot - 3;
                if (i >= 0 && i <= 60 && j >= 0 && j <= 60) {
                    float uu = u[(b * 64 + c0 + cc) * PLANE + i * 61 + j];
                    val = fmaxf(uu - LAMF, 0.f);
                }
            }
            lds[idx] = val;
        }
        __syncthreads();

        const float* fb = f1 + ((ru * 64 + c0) * 4) * 16;  // -> [cc][ii][16]
        for (int cc = 0; cc < 32; ++cc) {
#pragma unroll
            for (int ii = 0; ii < 4; ++ii) {
                const float* fp = fb + (cc * 4 + ii) * 16;
                int base = (ii * 32 + cc) * 64 + q;
                float a0 = lds[base + 0];
                float a1 = lds[base + 1];
                float a2 = lds[base + 2];
                float a3 = lds[base + 3];
                acc0 += a0 * fp[0]  + a1 * fp[1]  + a2 * fp[2]  + a3 * fp[3];
                acc1 += a0 * fp[4]  + a1 * fp[5]  + a2 * fp[6]  + a3 * fp[7];
                acc2 += a0 * fp[8]  + a1 * fp[9]  + a2 * fp[10] + a3 * fp[11];
                acc3 += a0 * fp[12] + a1 * fp[13] + a2 * fp[14] + a3 * fp[15];
            }
        }
    }

    int x = 4 * q + r;
    int gi = (b * 256 + 4 * p0) * 256 + x;
    e[gi]           = img[gi]           - acc0;
    e[gi + 256]     = img[gi + 256]     - acc1;
    e[gi + 512]     = img[gi + 512]     - acc2;
    e[gi + 768]     = img[gi + 768]     - acc3;
}

// ---------------------------------------------------------------------------
// Kernel 2: acc[b,i,j,c] = sum_{kh,kw} e[b,4i+kh,4j+kw] * filt[kh,kw,c]
// then g = -u + acc + relu(u-lam), Adam update of (u,m,v) in place.
// block = (b,i); e patch 16x256 staged in LDS (shared by all 64 channels);
// thread = (j lane, 16-channel strip c0..c0+15), c0 wave-uniform -> s_loads.
// ---------------------------------------------------------------------------
__global__ __launch_bounds__(256) void gk(float* __restrict__ u,
                                          float* __restrict__ mbuf,
                                          float* __restrict__ vbuf,
                                          const float* __restrict__ e,
                                          const float* __restrict__ filt,
                                          float bc1, float bc2) {
    __shared__ __align__(16) float lds[16 * 256];
    int bx  = blockIdx.x;
    int b   = bx / 61;
    int i   = bx % 61;
    int tid = threadIdx.x;
    int j   = tid & 63;
    int c0  = __builtin_amdgcn_readfirstlane((tid >> 6) * 16);
    int jc  = (j < 61) ? j : 60;   // keep lds reads of idle lanes in-bounds

    for (int idx = tid; idx < 4096; idx += 256) {
        int row = idx >> 8, col = idx & 255;
        lds[idx] = e[(b * 256 + 4 * i + row) * 256 + col];
    }
    __syncthreads();

    float acc[16];
#pragma unroll
    for (int t = 0; t < 16; ++t) acc[t] = 0.f;

    for (int kh = 0; kh < 16; ++kh) {
        const float* frow = filt + (kh * 16) * 64 + c0;
#pragma unroll
        for (int g = 0; g < 4; ++g) {
            const float4 e4 = *(const float4*)&lds[kh * 256 + 4 * jc + 4 * g];
            const float ev[4] = {e4.x, e4.y, e4.z, e4.w};
#pragma unroll
            for (int t = 0; t < 4; ++t) {
                const float* fc = frow + (4 * g + t) * 64;
                float evv = ev[t];
#pragma unroll
                for (int mm = 0; mm < 16; ++mm)
                    acc[mm] += evv * fc[mm];
            }
        }
    }

    if (j < 61) {
#pragma unroll
        for (int mm = 0; mm < 16; ++mm) {
            int c = c0 + mm;
            int idx = (b * 64 + c) * PLANE + i * 61 + j;
            float uu = u[idx];
            float a  = fmaxf(uu - LAMF, 0.f);
            float g  = acc[mm] + a - uu;
            float mv = B1F * mbuf[idx] + (1.f - B1F) * g;
            float vv = B2F * vbuf[idx] + (1.f - B2F) * g * g;
            mbuf[idx] = mv;
            vbuf[idx] = vv;
            float mh = mv / bc1;
            float vh = vv / bc2;
            u[idx] = uu + LRF * mh / (sqrtf(vh) + EPSF);
        }
    }
}

// ---------------------------------------------------------------------------
// Final: out[b,i,j,c] = relu(u[b,c,i,j] - lam)  (NHWC transpose via LDS)
// ---------------------------------------------------------------------------
__global__ __launch_bounds__(256) void outk(const float* __restrict__ u,
                                            float* __restrict__ out) {
    __shared__ float lds[64 * 61];
    int bx  = blockIdx.x;
    int b   = bx / 61;
    int i   = bx % 61;
    int tid = threadIdx.x;
    for (int idx = tid; idx < 64 * 61; idx += 256) {
        int c = idx / 61, j = idx % 61;
        float uu = u[(b * 64 + c) * PLANE + i * 61 + j];
        lds[idx] = fmaxf(uu - LAMF, 0.f);
    }
    __syncthreads();
    for (int idx = tid; idx < 61 * 64; idx += 256) {
        int jj = idx >> 6, c = idx & 63;
        out[((b * 61 + i) * 61 + jj) * 64 + c] = lds[c * 61 + jj];
    }
}

// ---------------------------------------------------------------------------
extern "C" void kernel_launch(void* const* d_in, const int* in_sizes, int n_in,
                              void* d_out, int out_size, void* d_ws, size_t ws_size,
                              hipStream_t stream) {
    const float* img  = (const float*)d_in[0];
    const float* filt = (const float*)d_in[1];
    float* out  = (float*)d_out;

    float* u    = (float*)d_ws;
    float* mbuf = u + USZ;
    float* vbuf = mbuf + USZ;
    float* e    = vbuf + USZ;
    float* f1   = e + ESZ;

    hipMemsetAsync(u, 0, (size_t)3 * USZ * sizeof(float), stream);
    permute_filt<<<FSZ / 256, 256, 0, stream>>>(filt, f1);

    float b1p = 1.f, b2p = 1.f;
    for (int t = 0; t < 10; ++t) {
        b1p *= B1F;
        b2p *= B2F;
        ek<<<NB * 64, 256, 0, stream>>>(u, img, f1, e);
        gk<<<NB * 61, 256, 0, stream>>>(u, mbuf, vbuf, e, filt,
                                        1.f - b1p, 1.f - b2p);
    }
    outk<<<NB * 61, 256, 0, stream>>>(u, out);
}

// Round 3
// 1482.733 us; speedup vs baseline: 1.4011x; 1.4011x over previous
//
#include <hip/hip_runtime.h>

#define LAMF 0.1f
#define LRF  0.01f
#define B1F  0.9f
#define B2F  0.99f
#define EPSF 1e-8f

constexpr int NB = 32, H = 256, W = 256, C = 64;
constexpr int OH = 61, OW = 61;
constexpr int PLANE = OH * OW;             // 3721
constexpr int USZ = NB * C * PLANE;        // 7,620,608 floats
constexpr int ESZ = NB * H * W;            // 2,097,152 floats
constexpr int FSZ = 16 * 16 * 64;          // 16384 floats
// act_pad: [b][c][62 rows][68 slots]; row 61 = permanent zero row (clamp target),
// slots 0..3 and 65..67 = permanent zero j-pad; interior j at slot j+4.
constexpr int APROW = 68;                  // dwords per row (16B aligned: 272B)
constexpr int APPL  = 62 * APROW;          // 4216 dwords per (b,c) plane
constexpr int APSZ  = NB * C * APPL;       // 8,634,368 floats

// ---------------------------------------------------------------------------
// f1[r][c][ii][s][k] = filt[4*(3-ii)+s][4*(3-k)+r][c]   (16 consecutive = [s][k])
// ---------------------------------------------------------------------------
__global__ __launch_bounds__(256) void permute_filt(const float* __restrict__ filt,
                                                    float* __restrict__ f1) {
    int o = blockIdx.x * 256 + threadIdx.x;
    if (o >= FSZ) return;
    int k  = o & 3;
    int s  = (o >> 2) & 3;
    int ii = (o >> 4) & 3;
    int c  = (o >> 6) & 63;
    int r  = o >> 12;
    int kh = 4 * (3 - ii) + s;
    int kw = 4 * (3 - k) + r;
    f1[o] = filt[(kh * 16 + kw) * 64 + c];
}

// ---------------------------------------------------------------------------
// ek: e[b,y,x] = img[b,y,x] - sum_{c,taps} act[...]*filt[...]
// block: (b, p0-group of 4 bands).  wave = phase r (x%4).
// lane = (w = band 0..3, xh = x/16).  thread outputs: s(4) x d(4), x=16xh+4d+r,
// y = 4*(p0+w)+s.  act window j in [4xh-3, 4xh+3] -> two aligned dwordx4 from
// global act_pad (zero-padded; out-of-range rows clamp to zero row 61).
// Filter taps wave-uniform -> s_load_dwordx16 from f1.
// ---------------------------------------------------------------------------
#define EK_LOAD(AR, cc)                                        \
  _Pragma("unroll")                                            \
  for (int li = 0; li < 4; ++li) {                             \
    const float* ap = rowp[li] + (cc) * APPL;                  \
    AR[li][0] = *(const float4*)ap;                            \
    AR[li][1] = *(const float4*)(ap + 4);                      \
  }

#define EK_FMA(AR, cc)                                                        \
  {                                                                           \
    const float* fs0 = fbase + (cc) * 64;                                     \
    _Pragma("unroll")                                                         \
    for (int li = 0; li < 4; ++li) {                                          \
      float av[8] = {AR[li][0].x, AR[li][0].y, AR[li][0].z, AR[li][0].w,      \
                     AR[li][1].x, AR[li][1].y, AR[li][1].z, AR[li][1].w};     \
      const float* fs = fs0 + li * 16;                                        \
      _Pragma("unroll")                                                       \
      for (int s = 0; s < 4; ++s) {                                           \
        _Pragma("unroll")                                                     \
        for (int d = 0; d < 4; ++d) {                                         \
          acc[s][d] += av[1 + d + 0] * fs[s * 4 + 0]                          \
                     + av[1 + d + 1] * fs[s * 4 + 1]                          \
                     + av[1 + d + 2] * fs[s * 4 + 2]                          \
                     + av[1 + d + 3] * fs[s * 4 + 3];                         \
        }                                                                     \
      }                                                                       \
    }                                                                         \
  }

__global__ __launch_bounds__(256) void ek(const float* __restrict__ act,
                                          const float* __restrict__ img,
                                          const float* __restrict__ f1,
                                          float* __restrict__ e) {
    int bid  = blockIdx.x;                     // 512 blocks = 8 XCD * 64
    int n    = (bid & 7) * 64 + (bid >> 3);    // XCD-contiguous swizzle
    int b    = n >> 4;
    int pg   = n & 15;
    int p0   = pg * 4;
    int tid  = threadIdx.x;
    int r    = __builtin_amdgcn_readfirstlane(tid >> 6);
    int lane = tid & 63;
    int w    = lane >> 4;
    int xh   = lane & 15;

    // per-li row base pointers (row clamped to permanent zero row 61)
    const float* rowp[4];
#pragma unroll
    for (int li = 0; li < 4; ++li) {
        int i   = p0 + w - 3 + li;
        int row = (i >= 0 && i <= 60) ? i : 61;
        rowp[li] = act + (size_t)((b * 64) * 62 + row) * APROW + 4 * xh;
    }

    float acc[4][4] = {};
    const float* fbase = f1 + r * 4096;        // f1[r][c][li][s][k]

    float4 Abuf[4][2], Bbuf[4][2];
    EK_LOAD(Abuf, 0);
    for (int c = 0; c < 64; c += 2) {
        EK_LOAD(Bbuf, c + 1);
        EK_FMA(Abuf, c);
        if (c + 2 < 64) EK_LOAD(Abuf, c + 2);
        EK_FMA(Bbuf, c + 1);
    }

    int ybase = 4 * (p0 + w);
    int xbase = 16 * xh + r;
#pragma unroll
    for (int s = 0; s < 4; ++s) {
        size_t gi = ((size_t)b * 256 + ybase + s) * 256 + xbase;
#pragma unroll
        for (int d = 0; d < 4; ++d)
            e[gi + 4 * d] = img[gi + 4 * d] - acc[s][d];
    }
}

// ---------------------------------------------------------------------------
// gk: acc[b,i,j,c] = sum_{kh,kw} e[b,4i+kh,4j+kw]*filt[kh,kw,c]; fused Adam;
// writes u,m,v and act_pad (act of the NEW u).  2 output rows per block
// (shared 20-row e patch in LDS).  FIRST=true: u=m=v=0 on input (write-only).
// ---------------------------------------------------------------------------
template <bool FIRST>
__global__ __launch_bounds__(256) void gk(float* __restrict__ u,
                                          float* __restrict__ mbuf,
                                          float* __restrict__ vbuf,
                                          float* __restrict__ actp,
                                          const float* __restrict__ e,
                                          const float* __restrict__ filt,
                                          float bc1, float bc2) {
    __shared__ __align__(16) float lds[20 * 256];
    int bid = blockIdx.x;                      // 992 = 8 * 124
    int n   = (bid & 7) * 124 + (bid >> 3);
    int b   = n / 31;
    int ip  = n % 31;
    int i0  = ip * 2;                          // i0, i0+1 (i0+1 masked if ==61)
    int tid = threadIdx.x;
    int j   = tid & 63;
    int c0  = __builtin_amdgcn_readfirstlane((tid >> 6) * 16);
    int jc  = (j < 61) ? j : 60;

    // stage e rows 4*i0 .. 4*i0+19 as float4
    const float4* e4 = (const float4*)(e + ((size_t)b * 256 + 4 * i0) * 256);
    float4* l4 = (float4*)lds;
    for (int idx = tid; idx < 20 * 64; idx += 256) {
        int row = idx >> 6;
        float4 v = make_float4(0.f, 0.f, 0.f, 0.f);
        if (4 * i0 + row < 256) v = e4[idx];
        l4[idx] = v;
    }
    __syncthreads();

    float acc[2][16] = {};
    for (int kh = 0; kh < 16; ++kh) {
#pragma unroll
        for (int gw = 0; gw < 4; ++gw) {
            float4 ea = l4[kh * 64 + jc + gw];
            float4 eb = l4[(kh + 4) * 64 + jc + gw];
            float eav[4] = {ea.x, ea.y, ea.z, ea.w};
            float ebv[4] = {eb.x, eb.y, eb.z, eb.w};
#pragma unroll
            for (int t = 0; t < 4; ++t) {
                const float* fc = filt + ((kh * 16 + 4 * gw + t) * 64 + c0);
                float ev0 = eav[t], ev1 = ebv[t];
#pragma unroll
                for (int mm = 0; mm < 16; ++mm) {
                    float f = fc[mm];
                    acc[0][mm] += ev0 * f;
                    acc[1][mm] += ev1 * f;
                }
            }
        }
    }

#pragma unroll
    for (int rr = 0; rr < 2; ++rr) {
        int i = i0 + rr;
        if (i <= 60 && j <= 60) {
#pragma unroll
            for (int mm = 0; mm < 16; ++mm) {
                size_t idx = (size_t)(b * 64 + c0 + mm) * PLANE + i * 61 + j;
                float gg = acc[rr][mm];
                float uu, a;
                if (FIRST) { uu = 0.f; a = 0.f; }
                else { uu = u[idx]; a = fmaxf(uu - LAMF, 0.f); }
                gg += a - uu;
                float mv, vv;
                if (FIRST) {
                    mv = (1.f - B1F) * gg;
                    vv = (1.f - B2F) * gg * gg;
                } else {
                    mv = B1F * mbuf[idx] + (1.f - B1F) * gg;
                    vv = B2F * vbuf[idx] + (1.f - B2F) * gg * gg;
                }
                mbuf[idx] = mv;
                vbuf[idx] = vv;
                float un = uu + LRF * (mv / bc1) / (sqrtf(vv / bc2) + EPSF);
                u[idx] = un;
                actp[(size_t)(b * 64 + c0 + mm) * APPL + (size_t)i * APROW + 4 + j]
                    = fmaxf(un - LAMF, 0.f);
            }
        }
    }
}

// ---------------------------------------------------------------------------
// out[b,i,j,c] = relu(u[b,c,i,j] - lam)  (NHWC transpose via LDS)
// ---------------------------------------------------------------------------
__global__ __launch_bounds__(256) void outk(const float* __restrict__ u,
                                            float* __restrict__ out) {
    __shared__ float lds[64 * 61];
    int bx  = blockIdx.x;
    int b   = bx / 61;
    int i   = bx % 61;
    int tid = threadIdx.x;
    for (int idx = tid; idx < 64 * 61; idx += 256) {
        int c = idx / 61, j = idx % 61;
        float uu = u[(size_t)(b * 64 + c) * PLANE + i * 61 + j];
        lds[idx] = fmaxf(uu - LAMF, 0.f);
    }
    __syncthreads();
    for (int idx = tid; idx < 61 * 64; idx += 256) {
        int jj = idx >> 6, c = idx & 63;
        out[(((size_t)b * 61 + i) * 61 + jj) * 64 + c] = lds[c * 61 + jj];
    }
}

// ---------------------------------------------------------------------------
extern "C" void kernel_launch(void* const* d_in, const int* in_sizes, int n_in,
                              void* d_out, int out_size, void* d_ws, size_t ws_size,
                              hipStream_t stream) {
    const float* img  = (const float*)d_in[0];
    const float* filt = (const float*)d_in[1];
    float* out = (float*)d_out;

    float* u    = (float*)d_ws;
    float* mbuf = u + USZ;
    float* vbuf = mbuf + USZ;
    float* e    = vbuf + USZ;
    float* f1   = e + ESZ;
    float* actp = f1 + FSZ;

    hipMemsetAsync(actp, 0, (size_t)APSZ * sizeof(float), stream);
    permute_filt<<<FSZ / 256, 256, 0, stream>>>(filt, f1);
    // t = 0: u = 0 -> act = 0 -> e = img exactly
    hipMemcpyAsync(e, img, (size_t)ESZ * sizeof(float), hipMemcpyDeviceToDevice,
                   stream);

    float b1p = B1F, b2p = B2F;
    gk<true><<<992, 256, 0, stream>>>(u, mbuf, vbuf, actp, e, filt,
                                      1.f - b1p, 1.f - b2p);
    for (int t = 1; t < 10; ++t) {
        b1p *= B1F;
        b2p *= B2F;
        ek<<<512, 256, 0, stream>>>(actp, img, f1, e);
        gk<false><<<992, 256, 0, stream>>>(u, mbuf, vbuf, actp, e, filt,
                                           1.f - b1p, 1.f - b2p);
    }
    outk<<<NB * 61, 256, 0, stream>>>(u, out);
}